// Round 1
// baseline (342.748 us; speedup 1.0000x reference)
//
#include <hip/hip_runtime.h>
#include <math.h>

#define N_NODES 50000
#define N_EDGES 1600000
#define BT 48           // B*T columns
#define MAXCAP 80       // ELL capacity; degree ~ Poisson(32), P(any node > 80) ~ 4e-8

// ---------------- init: deg = 1 (self loop weight), cnt = 0 ----------------
__global__ __launch_bounds__(256) void init_k(float* __restrict__ deg, int* __restrict__ cnt) {
  int n = blockIdx.x * 256 + threadIdx.x;
  if (n < N_NODES) { deg[n] = 1.0f; cnt[n] = 0; }
}

// ---------------- ELL build + weighted in-degree ----------------
__global__ __launch_bounds__(256) void fill_k(const int* __restrict__ ei,
                                              const float* __restrict__ ew,
                                              float* __restrict__ deg,
                                              int* __restrict__ cnt,
                                              int* __restrict__ esrc,
                                              float* __restrict__ ewgt,
                                              int cap) {
  int e = blockIdx.x * 256 + threadIdx.x;
  if (e >= N_EDGES) return;
  int s = ei[e];             // row 0: src
  int d = ei[N_EDGES + e];   // row 1: dst
  float w = ew[e];
  atomicAdd(&deg[d], w);
  int slot = atomicAdd(&cnt[d], 1);
  if (slot < cap) {
    esrc[(size_t)d * cap + slot] = s;
    ewgt[(size_t)d * cap + slot] = w;
  }
}

// ---------------- dinv = deg^-0.5 ----------------
__global__ __launch_bounds__(256) void dinv_k(const float* __restrict__ deg, float* __restrict__ dinv) {
  int n = blockIdx.x * 256 + threadIdx.x;
  if (n < N_NODES) {
    float dg = deg[n];
    dinv[n] = (dg > 0.0f) ? (1.0f / sqrtf(dg)) : 0.0f;
  }
}

// ---------------- transpose x_seq [BT, N] -> xt [N, BT] ----------------
__global__ __launch_bounds__(256) void transpose_k(const float* __restrict__ x, float* __restrict__ xt) {
  int n = blockIdx.x * 256 + threadIdx.x;
  if (n >= N_NODES) return;
  float tmp[BT];
#pragma unroll
  for (int bt = 0; bt < BT; ++bt) tmp[bt] = x[(size_t)bt * N_NODES + n];  // coalesced per bt
  float4* dst = (float4*)(xt + (size_t)n * BT);
#pragma unroll
  for (int j = 0; j < BT / 4; ++j)
    dst[j] = make_float4(tmp[4 * j], tmp[4 * j + 1], tmp[4 * j + 2], tmp[4 * j + 3]);
}

// ---------------- SpMM: one wave per node, 48 active lanes = bt columns ----------------
__global__ __launch_bounds__(256) void spmm_k(const float* __restrict__ xt,
                                              const int* __restrict__ esrc,
                                              const float* __restrict__ ewgt,
                                              const int* __restrict__ cnt,
                                              const float* __restrict__ dinv,
                                              float* __restrict__ agg,
                                              int cap) {
  int lane = threadIdx.x & 63;
  int n = __builtin_amdgcn_readfirstlane((blockIdx.x * 256 + threadIdx.x) >> 6);
  if (n >= N_NODES) return;
  int col = (lane < BT) ? lane : (BT - 1);  // lanes 48..63 duplicate col 47 (result discarded)

  const int*   sp = esrc + (size_t)n * cap;
  const float* wp = ewgt + (size_t)n * cap;
  float dn = dinv[n];
  int c = __builtin_amdgcn_readfirstlane(cnt[n]);
  if (c > cap) c = cap;

  float xn = xt[n * BT + col];
  float acc = 0.0f;

  int i = 0;
  for (; i + 4 <= c; i += 4) {   // 4-deep gather ILP; src/w/dinv[src] are wave-uniform -> SGPR
    int s0 = __builtin_amdgcn_readfirstlane(sp[i]);
    int s1 = __builtin_amdgcn_readfirstlane(sp[i + 1]);
    int s2 = __builtin_amdgcn_readfirstlane(sp[i + 2]);
    int s3 = __builtin_amdgcn_readfirstlane(sp[i + 3]);
    float c0 = wp[i]     * dinv[s0];
    float c1 = wp[i + 1] * dinv[s1];
    float c2 = wp[i + 2] * dinv[s2];
    float c3 = wp[i + 3] * dinv[s3];
    acc = fmaf(c0, xt[s0 * BT + col], acc);
    acc = fmaf(c1, xt[s1 * BT + col], acc);
    acc = fmaf(c2, xt[s2 * BT + col], acc);
    acc = fmaf(c3, xt[s3 * BT + col], acc);
  }
  for (; i < c; ++i) {
    int s = __builtin_amdgcn_readfirstlane(sp[i]);
    acc = fmaf(wp[i] * dinv[s], xt[s * BT + col], acc);
  }

  acc = dn * fmaf(dn, xn, acc);  // + self loop dinv^2 * x_n, then outer dinv_n factor
  if (lane < BT) agg[n * BT + col] = acc;
}

// ---------------- fold conv_w through the (rank-1) GCN weight ----------------
__global__ void coeff_k(const float* __restrict__ conv_w, const float* __restrict__ gcn_w,
                        const float* __restrict__ gcn_b, float* __restrict__ wv,
                        float* __restrict__ wb) {
  int idx = threadIdx.x;
  if (idx >= 96) return;
  int co = idx / 3, k = idx % 3;
  float sv = 0.0f, sb = 0.0f;
  for (int ci = 0; ci < 32; ++ci) {
    float w = conv_w[co * 96 + ci * 3 + k];  // [32,32,3]
    sv += w * gcn_w[ci];                     // gcn_w shape (1,32)
    sb += w * gcn_b[ci];
  }
  wv[idx] = sv;
  wb[idx] = sb;
}

// ---------------- epilogue: conv3 + relu + mean + linear, closed form per (b,n) ----------------
__global__ __launch_bounds__(256) void epi_k(const float* __restrict__ agg,
                                             const float* __restrict__ wv,
                                             const float* __restrict__ wb,
                                             const float* __restrict__ conv_b,
                                             const float* __restrict__ lin_w,
                                             const float* __restrict__ lin_b,
                                             float* __restrict__ out) {
  __shared__ float s_wv[96], s_wb[96], s_cb[32], s_lw[32], s_lb;
  int tid = threadIdx.x;
  if (tid < 96) { s_wv[tid] = wv[tid]; s_wb[tid] = wb[tid]; }
  if (tid < 32) { s_cb[tid] = conv_b[tid]; s_lw[tid] = lin_w[tid]; }
  if (tid == 0) s_lb = lin_b[0];
  __syncthreads();

  int n = blockIdx.x * 256 + tid;
  if (n >= N_NODES) return;
  const float4* ap = (const float4*)(agg + (size_t)n * BT);

#pragma unroll
  for (int b = 0; b < 4; ++b) {
    float4 q0 = ap[b * 3], q1 = ap[b * 3 + 1], q2 = ap[b * 3 + 2];
    float a[14];  // a[0], a[13] are the zero pads; all indices compile-time
    a[0] = 0.0f; a[13] = 0.0f;
    a[1] = q0.x; a[2] = q0.y; a[3] = q0.z; a[4] = q0.w;
    a[5] = q1.x; a[6] = q1.y; a[7] = q1.z; a[8] = q1.w;
    a[9] = q2.x; a[10] = q2.y; a[11] = q2.z; a[12] = q2.w;

    float acc = 0.0f;
    for (int co = 0; co < 32; ++co) {
      float w0 = s_wv[3 * co], w1 = s_wv[3 * co + 1], w2 = s_wv[3 * co + 2];
      float b0 = s_wb[3 * co], b1 = s_wb[3 * co + 1], b2 = s_wb[3 * co + 2];
      float base = s_cb[co] + b1;
      float lw = s_lw[co];
      float sr = 0.0f;
#pragma unroll
      for (int t = 0; t < 12; ++t) {
        float v = base + w0 * a[t] + w1 * a[t + 1] + w2 * a[t + 2];
        if (t > 0)  v += b0;   // bias only where the conv window overlaps valid h
        if (t < 11) v += b2;
        sr += fmaxf(v, 0.0f);
      }
      acc = fmaf(lw, sr, acc);
    }
    out[b * N_NODES + n] = s_lb + acc * (1.0f / 12.0f);
  }
}

extern "C" void kernel_launch(void* const* d_in, const int* in_sizes, int n_in,
                              void* d_out, int out_size, void* d_ws, size_t ws_size,
                              hipStream_t stream) {
  const float* x_seq  = (const float*)d_in[0];
  const int*   ei     = (const int*)d_in[1];   // [2, E] int32 per harness contract
  const float* ew     = (const float*)d_in[2];
  const float* gcn_w  = (const float*)d_in[3];
  const float* gcn_b  = (const float*)d_in[4];
  const float* conv_w = (const float*)d_in[5];
  const float* conv_b = (const float*)d_in[6];
  const float* lin_w  = (const float*)d_in[7];
  const float* lin_b  = (const float*)d_in[8];
  float* out = (float*)d_out;

  char* ws = (char*)d_ws;
  size_t off = 0;
  auto alloc = [&](size_t bytes) -> void* {
    void* p = ws + off;
    off += (bytes + 511) & ~(size_t)511;
    return p;
  };
  float* xt   = (float*)alloc((size_t)N_NODES * BT * 4);
  float* agg  = (float*)alloc((size_t)N_NODES * BT * 4);
  float* deg  = (float*)alloc((size_t)N_NODES * 4);
  float* dinv = (float*)alloc((size_t)N_NODES * 4);
  int*   cnt  = (int*)alloc((size_t)N_NODES * 4);
  float* wv   = (float*)alloc(96 * 4);
  float* wb   = (float*)alloc(96 * 4);

  // ELL capacity: 80 if scratch allows, else degrade (still correct for cap >= max degree ~65)
  int cap = MAXCAP;
  if (ws_size > off) {
    size_t remain = ws_size - off;
    size_t cap_fit = remain / ((size_t)N_NODES * 8);
    if (cap_fit < (size_t)cap) cap = (int)cap_fit;
  }
  if (cap < 1) cap = 1;
  int*   esrc = (int*)alloc((size_t)N_NODES * cap * 4);
  float* ewgt = (float*)alloc((size_t)N_NODES * cap * 4);

  const int nblk = (N_NODES + 255) / 256;
  const int eblk = (N_EDGES + 255) / 256;

  hipLaunchKernelGGL(init_k, dim3(nblk), dim3(256), 0, stream, deg, cnt);
  hipLaunchKernelGGL(fill_k, dim3(eblk), dim3(256), 0, stream, ei, ew, deg, cnt, esrc, ewgt, cap);
  hipLaunchKernelGGL(dinv_k, dim3(nblk), dim3(256), 0, stream, deg, dinv);
  hipLaunchKernelGGL(transpose_k, dim3(nblk), dim3(256), 0, stream, x_seq, xt);
  hipLaunchKernelGGL(spmm_k, dim3((N_NODES * 64 + 255) / 256), dim3(256), 0, stream,
                     xt, esrc, ewgt, cnt, dinv, agg, cap);
  hipLaunchKernelGGL(coeff_k, dim3(1), dim3(128), 0, stream, conv_w, gcn_w, gcn_b, wv, wb);
  hipLaunchKernelGGL(epi_k, dim3(nblk), dim3(256), 0, stream, agg, wv, wb, conv_b, lin_w, lin_b, out);
}

// Round 2
// 305.985 us; speedup vs baseline: 1.1201x; 1.1201x over previous
//
#include <hip/hip_runtime.h>
#include <math.h>

#define N_NODES 50000
#define N_EDGES 1600000
#define BT 48           // B*T columns
#define MAXCAP 80       // ELL capacity; degree ~ Poisson(32), P(any node > 80) ~ 4e-8

// ---------------- init: cnt = 0 ----------------
__global__ __launch_bounds__(256) void init_k(int* __restrict__ cnt) {
  int n = blockIdx.x * 256 + threadIdx.x;
  if (n < N_NODES) cnt[n] = 0;
}

// ---------------- ELL build: one atomic + one packed 8B store per edge ----------------
__global__ __launch_bounds__(256) void fill_k(const int* __restrict__ ei,
                                              const float* __restrict__ ew,
                                              int* __restrict__ cnt,
                                              int2* __restrict__ ell,
                                              int cap) {
  int e0 = 2 * (blockIdx.x * 256 + threadIdx.x);
  if (e0 >= N_EDGES) return;
  int2   s2 = *(const int2*)(ei + e0);             // srcs (row 0)
  int2   d2 = *(const int2*)(ei + N_EDGES + e0);   // dsts (row 1)
  float2 w2 = *(const float2*)(ew + e0);

  int slot0 = atomicAdd(&cnt[d2.x], 1);
  int slot1 = atomicAdd(&cnt[d2.y], 1);
  if (slot0 < cap) ell[(size_t)d2.x * cap + slot0] = make_int2(s2.x, __float_as_int(w2.x));
  if (slot1 < cap) ell[(size_t)d2.y * cap + slot1] = make_int2(s2.y, __float_as_int(w2.y));
}

// ---------------- deg from ELL row, dinv = (1+sum_w)^-0.5 ; wave per node ----------------
__global__ __launch_bounds__(256) void deg_k(const int2* __restrict__ ell,
                                             const int* __restrict__ cnt,
                                             float* __restrict__ dinv,
                                             int cap) {
  int lane = threadIdx.x & 63;
  int n = (blockIdx.x * 256 + threadIdx.x) >> 6;
  if (n >= N_NODES) return;
  int c = cnt[n];
  if (c > cap) c = cap;
  const int2* row = ell + (size_t)n * cap;
  float s = 0.0f;
  for (int i = lane; i < c; i += 64) s += __int_as_float(row[i].y);
#pragma unroll
  for (int off = 32; off >= 1; off >>= 1) s += __shfl_xor(s, off, 64);
  if (lane == 0) dinv[n] = 1.0f / sqrtf(1.0f + s);
}

// ---------------- transpose x_seq [BT, N] -> xt [N, BT] ----------------
__global__ __launch_bounds__(256) void transpose_k(const float* __restrict__ x, float* __restrict__ xt) {
  int n = blockIdx.x * 256 + threadIdx.x;
  if (n >= N_NODES) return;
  float tmp[BT];
#pragma unroll
  for (int bt = 0; bt < BT; ++bt) tmp[bt] = x[(size_t)bt * N_NODES + n];  // coalesced per bt
  float4* dst = (float4*)(xt + (size_t)n * BT);
#pragma unroll
  for (int j = 0; j < BT / 4; ++j)
    dst[j] = make_float4(tmp[4 * j], tmp[4 * j + 1], tmp[4 * j + 2], tmp[4 * j + 3]);
}

// ---------------- SpMM: one wave per node, 48 active lanes = bt columns ----------------
__global__ __launch_bounds__(256) void spmm_k(const float* __restrict__ xt,
                                              const int2* __restrict__ ell,
                                              const int* __restrict__ cnt,
                                              const float* __restrict__ dinv,
                                              float* __restrict__ agg,
                                              int cap) {
  int lane = threadIdx.x & 63;
  int n = __builtin_amdgcn_readfirstlane((blockIdx.x * 256 + threadIdx.x) >> 6);
  if (n >= N_NODES) return;
  int col = (lane < BT) ? lane : (BT - 1);  // lanes 48..63 duplicate col 47 (no extra lines)

  const int2* pp = ell + (size_t)n * cap;
  float dn = dinv[n];
  int c = __builtin_amdgcn_readfirstlane(cnt[n]);
  if (c > cap) c = cap;

  float xn = xt[n * BT + col];
  float acc = 0.0f;

  int i = 0;
  for (; i + 4 <= c; i += 4) {   // 4-deep gather ILP; per-edge metadata is wave-uniform -> SGPR
    int2 p0 = pp[i], p1 = pp[i + 1], p2 = pp[i + 2], p3 = pp[i + 3];
    int s0 = __builtin_amdgcn_readfirstlane(p0.x);
    int s1 = __builtin_amdgcn_readfirstlane(p1.x);
    int s2 = __builtin_amdgcn_readfirstlane(p2.x);
    int s3 = __builtin_amdgcn_readfirstlane(p3.x);
    float w0 = __int_as_float(__builtin_amdgcn_readfirstlane(p0.y));
    float w1 = __int_as_float(__builtin_amdgcn_readfirstlane(p1.y));
    float w2 = __int_as_float(__builtin_amdgcn_readfirstlane(p2.y));
    float w3 = __int_as_float(__builtin_amdgcn_readfirstlane(p3.y));
    float c0 = w0 * dinv[s0];
    float c1 = w1 * dinv[s1];
    float c2 = w2 * dinv[s2];
    float c3 = w3 * dinv[s3];
    acc = fmaf(c0, xt[s0 * BT + col], acc);
    acc = fmaf(c1, xt[s1 * BT + col], acc);
    acc = fmaf(c2, xt[s2 * BT + col], acc);
    acc = fmaf(c3, xt[s3 * BT + col], acc);
  }
  for (; i < c; ++i) {
    int2 p = pp[i];
    int s = __builtin_amdgcn_readfirstlane(p.x);
    float w = __int_as_float(__builtin_amdgcn_readfirstlane(p.y));
    acc = fmaf(w * dinv[s], xt[s * BT + col], acc);
  }

  acc = dn * fmaf(dn, xn, acc);  // + self loop dinv^2 * x_n, then outer dinv_n factor
  if (lane < BT) agg[n * BT + col] = acc;
}

// ---------------- fold conv_w through the (rank-1) GCN weight ----------------
__global__ void coeff_k(const float* __restrict__ conv_w, const float* __restrict__ gcn_w,
                        const float* __restrict__ gcn_b, float* __restrict__ wv,
                        float* __restrict__ wb) {
  int idx = threadIdx.x;
  if (idx >= 96) return;
  int co = idx / 3, k = idx % 3;
  float sv = 0.0f, sb = 0.0f;
  for (int ci = 0; ci < 32; ++ci) {
    float w = conv_w[co * 96 + ci * 3 + k];  // [32,32,3]
    sv += w * gcn_w[ci];                     // gcn_w shape (1,32)
    sb += w * gcn_b[ci];
  }
  wv[idx] = sv;
  wb[idx] = sb;
}

// ---------------- epilogue: conv3 + relu + mean + linear, closed form per (b,n) ----------------
__global__ __launch_bounds__(256) void epi_k(const float* __restrict__ agg,
                                             const float* __restrict__ wv,
                                             const float* __restrict__ wb,
                                             const float* __restrict__ conv_b,
                                             const float* __restrict__ lin_w,
                                             const float* __restrict__ lin_b,
                                             float* __restrict__ out) {
  __shared__ float s_wv[96], s_wb[96], s_cb[32], s_lw[32], s_lb;
  int tid = threadIdx.x;
  if (tid < 96) { s_wv[tid] = wv[tid]; s_wb[tid] = wb[tid]; }
  if (tid < 32) { s_cb[tid] = conv_b[tid]; s_lw[tid] = lin_w[tid]; }
  if (tid == 0) s_lb = lin_b[0];
  __syncthreads();

  int n = blockIdx.x * 256 + tid;
  if (n >= N_NODES) return;
  const float4* ap = (const float4*)(agg + (size_t)n * BT);

#pragma unroll
  for (int b = 0; b < 4; ++b) {
    float4 q0 = ap[b * 3], q1 = ap[b * 3 + 1], q2 = ap[b * 3 + 2];
    float a[14];  // a[0], a[13] are the zero pads; all indices compile-time
    a[0] = 0.0f; a[13] = 0.0f;
    a[1] = q0.x; a[2] = q0.y; a[3] = q0.z; a[4] = q0.w;
    a[5] = q1.x; a[6] = q1.y; a[7] = q1.z; a[8] = q1.w;
    a[9] = q2.x; a[10] = q2.y; a[11] = q2.z; a[12] = q2.w;

    float acc = 0.0f;
    for (int co = 0; co < 32; ++co) {
      float w0 = s_wv[3 * co], w1 = s_wv[3 * co + 1], w2 = s_wv[3 * co + 2];
      float b0 = s_wb[3 * co], b1 = s_wb[3 * co + 1], b2 = s_wb[3 * co + 2];
      float base = s_cb[co] + b1;
      float lw = s_lw[co];
      float sr = 0.0f;
#pragma unroll
      for (int t = 0; t < 12; ++t) {
        float v = base + w0 * a[t] + w1 * a[t + 1] + w2 * a[t + 2];
        if (t > 0)  v += b0;   // bias only where the conv window overlaps valid h
        if (t < 11) v += b2;
        sr += fmaxf(v, 0.0f);
      }
      acc = fmaf(lw, sr, acc);
    }
    out[b * N_NODES + n] = s_lb + acc * (1.0f / 12.0f);
  }
}

extern "C" void kernel_launch(void* const* d_in, const int* in_sizes, int n_in,
                              void* d_out, int out_size, void* d_ws, size_t ws_size,
                              hipStream_t stream) {
  const float* x_seq  = (const float*)d_in[0];
  const int*   ei     = (const int*)d_in[1];   // [2, E] int32 per harness contract
  const float* ew     = (const float*)d_in[2];
  const float* gcn_w  = (const float*)d_in[3];
  const float* gcn_b  = (const float*)d_in[4];
  const float* conv_w = (const float*)d_in[5];
  const float* conv_b = (const float*)d_in[6];
  const float* lin_w  = (const float*)d_in[7];
  const float* lin_b  = (const float*)d_in[8];
  float* out = (float*)d_out;

  char* ws = (char*)d_ws;
  size_t off = 0;
  auto alloc = [&](size_t bytes) -> void* {
    void* p = ws + off;
    off += (bytes + 511) & ~(size_t)511;
    return p;
  };
  float* xt   = (float*)alloc((size_t)N_NODES * BT * 4);
  float* agg  = (float*)alloc((size_t)N_NODES * BT * 4);
  float* dinv = (float*)alloc((size_t)N_NODES * 4);
  int*   cnt  = (int*)alloc((size_t)N_NODES * 4);
  float* wv   = (float*)alloc(96 * 4);
  float* wb   = (float*)alloc(96 * 4);

  // ELL capacity: 80 if scratch allows, else degrade (still correct for cap >= max degree ~65)
  int cap = MAXCAP;
  if (ws_size > off) {
    size_t remain = ws_size - off;
    size_t cap_fit = remain / ((size_t)N_NODES * 8);
    if (cap_fit < (size_t)cap) cap = (int)cap_fit;
  }
  if (cap < 1) cap = 1;
  int2* ell = (int2*)alloc((size_t)N_NODES * cap * 8);

  const int nblk = (N_NODES + 255) / 256;
  const int eblk2 = (N_EDGES / 2 + 255) / 256;
  const int wblk = (N_NODES * 64 + 255) / 256;

  hipLaunchKernelGGL(init_k, dim3(nblk), dim3(256), 0, stream, cnt);
  hipLaunchKernelGGL(fill_k, dim3(eblk2), dim3(256), 0, stream, ei, ew, cnt, ell, cap);
  hipLaunchKernelGGL(deg_k, dim3(wblk), dim3(256), 0, stream, ell, cnt, dinv, cap);
  hipLaunchKernelGGL(transpose_k, dim3(nblk), dim3(256), 0, stream, x_seq, xt);
  hipLaunchKernelGGL(spmm_k, dim3(wblk), dim3(256), 0, stream, xt, ell, cnt, dinv, agg, cap);
  hipLaunchKernelGGL(coeff_k, dim3(1), dim3(128), 0, stream, conv_w, gcn_w, gcn_b, wv, wb);
  hipLaunchKernelGGL(epi_k, dim3(nblk), dim3(256), 0, stream, agg, wv, wb, conv_b, lin_w, lin_b, out);
}